// Round 1
// baseline (2056.484 us; speedup 1.0000x reference)
//
#include <hip/hip_runtime.h>

#define TPB 256

// A = deg (then overwritten with dinv), B = y = x*dinv, C = scatter accumulator
// (reused for both layers), D = z = h2*dinv.

__global__ void k_init(float* __restrict__ deg, float* __restrict__ num, int n) {
    int i = blockIdx.x * blockDim.x + threadIdx.x;
    if (i < n) { deg[i] = 1.0f; num[i] = 0.0f; }  // deg=1 accounts for self-loop
}

__global__ void k_deg(const int* __restrict__ dst, float* __restrict__ deg, int e) {
    int i = blockIdx.x * blockDim.x + threadIdx.x;
    if (i < e) atomicAdd(deg + dst[i], 1.0f);
}

__global__ void k_dinv(const float* __restrict__ x, float* __restrict__ deg_dinv,
                       float* __restrict__ y, int n) {
    int i = blockIdx.x * blockDim.x + threadIdx.x;
    if (i < n) {
        float d = rsqrtf(deg_dinv[i]);  // deg >= 1 always (self-loop), no zero case
        deg_dinv[i] = d;
        y[i] = x[i] * d;
    }
}

__global__ void k_scatter(const int* __restrict__ src, const int* __restrict__ dst,
                          const float* __restrict__ val, float* __restrict__ num, int e) {
    int i = blockIdx.x * blockDim.x + threadIdx.x;
    if (i < e) atomicAdd(num + dst[i], val[src[i]]);
}

__global__ void k_node(const float* __restrict__ dinv, const float* __restrict__ y,
                       float* __restrict__ num, float* __restrict__ z,
                       const float* __restrict__ W1, const float* __restrict__ b1,
                       const float* __restrict__ W2, int n, int f) {
    int i = blockIdx.x * blockDim.x + threadIdx.x;
    if (i < n) {
        float agg = dinv[i] * (num[i] + y[i]);  // + y[i]: self-loop contribution
        float h2 = 0.0f;
        for (int j = 0; j < f; j++) {
            float h = W1[j] * agg + b1[j];
            h2 += fmaxf(h, 0.0f) * W2[j];
        }
        z[i] = h2 * dinv[i];
        num[i] = 0.0f;  // reset accumulator for layer-2 scatter
    }
}

__global__ void k_out(const float* __restrict__ dinv, const float* __restrict__ z,
                      const float* __restrict__ num, const float* __restrict__ b2,
                      float* __restrict__ out, int n) {
    int i = blockIdx.x * blockDim.x + threadIdx.x;
    if (i < n) out[i] = dinv[i] * (num[i] + z[i]) + b2[0];  // + z[i]: self-loop
}

extern "C" void kernel_launch(void* const* d_in, const int* in_sizes, int n_in,
                              void* d_out, int out_size, void* d_ws, size_t ws_size,
                              hipStream_t stream) {
    const float* x  = (const float*)d_in[0];
    const int*   ei = (const int*)d_in[1];   // int64 values fit int32; harness ABI: integer -> int*
    const float* W1 = (const float*)d_in[2];
    const float* b1 = (const float*)d_in[3];
    const float* W2 = (const float*)d_in[4];
    const float* b2 = (const float*)d_in[5];

    int n = in_sizes[0];        // 200000
    int e = in_sizes[1] / 2;    // 12.8M
    int f = in_sizes[2];        // 16

    const int* src = ei;
    const int* dst = ei + e;

    float* A = (float*)d_ws;    // deg -> dinv
    float* B = A + n;           // y = x * dinv
    float* C = B + n;           // scatter accumulator (both layers)
    float* D = C + n;           // z = h2 * dinv
    float* out = (float*)d_out;

    int gn = (n + TPB - 1) / TPB;
    int ge = (e + TPB - 1) / TPB;

    k_init<<<gn, TPB, 0, stream>>>(A, C, n);
    k_deg<<<ge, TPB, 0, stream>>>(dst, A, e);
    k_dinv<<<gn, TPB, 0, stream>>>(x, A, B, n);
    k_scatter<<<ge, TPB, 0, stream>>>(src, dst, B, C, e);
    k_node<<<gn, TPB, 0, stream>>>(A, B, C, D, W1, b1, W2, n, f);
    k_scatter<<<ge, TPB, 0, stream>>>(src, dst, D, C, e);
    k_out<<<gn, TPB, 0, stream>>>(A, D, C, b2, out, n);
}

// Round 2
// 2051.728 us; speedup vs baseline: 1.0023x; 1.0023x over previous
//
#include <hip/hip_runtime.h>

#define TPB 256

// A = deg (then overwritten with dinv), B = y = x*dinv, C = scatter accumulator
// (reused for both layers), D = z = h2*dinv.
//
// R1 change: atomicAdd(float*) without -munsafe-fp-atomics compiles to a CAS
// loop (return-value round-trip + retries under contention) -> 409 MB HBM
// write-through and 654 us per scatter. unsafeAtomicAdd emits the native
// fire-and-forget global_atomic_add_f32 which resolves in L2.

__global__ void k_init(float* __restrict__ deg, float* __restrict__ num, int n) {
    int i = blockIdx.x * blockDim.x + threadIdx.x;
    if (i < n) { deg[i] = 1.0f; num[i] = 0.0f; }  // deg=1 accounts for self-loop
}

__global__ void k_deg(const int* __restrict__ dst, float* __restrict__ deg, int e) {
    int i = blockIdx.x * blockDim.x + threadIdx.x;
    if (i < e) unsafeAtomicAdd(deg + dst[i], 1.0f);
}

__global__ void k_dinv(const float* __restrict__ x, float* __restrict__ deg_dinv,
                       float* __restrict__ y, int n) {
    int i = blockIdx.x * blockDim.x + threadIdx.x;
    if (i < n) {
        float d = rsqrtf(deg_dinv[i]);  // deg >= 1 always (self-loop), no zero case
        deg_dinv[i] = d;
        y[i] = x[i] * d;
    }
}

__global__ void k_scatter(const int* __restrict__ src, const int* __restrict__ dst,
                          const float* __restrict__ val, float* __restrict__ num, int e) {
    int i = blockIdx.x * blockDim.x + threadIdx.x;
    if (i < e) unsafeAtomicAdd(num + dst[i], val[src[i]]);
}

__global__ void k_node(const float* __restrict__ dinv, const float* __restrict__ y,
                       float* __restrict__ num, float* __restrict__ z,
                       const float* __restrict__ W1, const float* __restrict__ b1,
                       const float* __restrict__ W2, int n, int f) {
    int i = blockIdx.x * blockDim.x + threadIdx.x;
    if (i < n) {
        float agg = dinv[i] * (num[i] + y[i]);  // + y[i]: self-loop contribution
        float h2 = 0.0f;
        for (int j = 0; j < f; j++) {
            float h = W1[j] * agg + b1[j];
            h2 += fmaxf(h, 0.0f) * W2[j];
        }
        z[i] = h2 * dinv[i];
        num[i] = 0.0f;  // reset accumulator for layer-2 scatter
    }
}

__global__ void k_out(const float* __restrict__ dinv, const float* __restrict__ z,
                      const float* __restrict__ num, const float* __restrict__ b2,
                      float* __restrict__ out, int n) {
    int i = blockIdx.x * blockDim.x + threadIdx.x;
    if (i < n) out[i] = dinv[i] * (num[i] + z[i]) + b2[0];  // + z[i]: self-loop
}

extern "C" void kernel_launch(void* const* d_in, const int* in_sizes, int n_in,
                              void* d_out, int out_size, void* d_ws, size_t ws_size,
                              hipStream_t stream) {
    const float* x  = (const float*)d_in[0];
    const int*   ei = (const int*)d_in[1];   // int64 values fit int32; harness ABI: integer -> int*
    const float* W1 = (const float*)d_in[2];
    const float* b1 = (const float*)d_in[3];
    const float* W2 = (const float*)d_in[4];
    const float* b2 = (const float*)d_in[5];

    int n = in_sizes[0];        // 200000
    int e = in_sizes[1] / 2;    // 12.8M
    int f = in_sizes[2];        // 16

    const int* src = ei;
    const int* dst = ei + e;

    float* A = (float*)d_ws;    // deg -> dinv
    float* B = A + n;           // y = x * dinv
    float* C = B + n;           // scatter accumulator (both layers)
    float* D = C + n;           // z = h2 * dinv
    float* out = (float*)d_out;

    int gn = (n + TPB - 1) / TPB;
    int ge = (e + TPB - 1) / TPB;

    k_init<<<gn, TPB, 0, stream>>>(A, C, n);
    k_deg<<<ge, TPB, 0, stream>>>(dst, A, e);
    k_dinv<<<gn, TPB, 0, stream>>>(x, A, B, n);
    k_scatter<<<ge, TPB, 0, stream>>>(src, dst, B, C, e);
    k_node<<<gn, TPB, 0, stream>>>(A, B, C, D, W1, b1, W2, n, f);
    k_scatter<<<ge, TPB, 0, stream>>>(src, dst, D, C, e);
    k_out<<<gn, TPB, 0, stream>>>(A, D, C, b2, out, n);
}

// Round 3
// 1734.045 us; speedup vs baseline: 1.1859x; 1.1832x over previous
//
#include <hip/hip_runtime.h>

#define TPB 256
#define LOG_S 14
#define S (1 << LOG_S)   // 16384 nodes per range -> 64 KB LDS per block
#define MAXC 32

// ---------------- new path: LDS-partitioned scatter, no device atomics ------
// Grid = R * bpr blocks. Block (r,c): scan edge stripe c, accumulate dst in
// range r into LDS via ds_add_f32, then STORE (not atomic) 16K floats to
// partials[(r*bpr+c)*S .. +S). Reduce kernels sum over c (fused w/ pointwise).

template <bool DEG>
__global__ __launch_bounds__(TPB) void k_scat(const int* __restrict__ dst,
                                              const int* __restrict__ src,
                                              const float* __restrict__ val,
                                              float* __restrict__ partials,
                                              int e, int bpr) {
    __shared__ float acc[S];
    const int t = threadIdx.x;
    const int r = blockIdx.x / bpr;
    const int c = blockIdx.x - r * bpr;
    const int rlo = r << LOG_S;

    for (int j = t; j < S; j += TPB) acc[j] = 0.0f;
    __syncthreads();

    const int stride = bpr * TPB;          // in int4 units below
    const int e4 = e >> 2;
    const int4* dst4 = (const int4*)dst;

    for (int i = c * TPB + t; i < e4; i += stride) {
        int4 d4 = dst4[i];
        int idx = i << 2;
        unsigned l0 = (unsigned)(d4.x - rlo);
        unsigned l1 = (unsigned)(d4.y - rlo);
        unsigned l2 = (unsigned)(d4.z - rlo);
        unsigned l3 = (unsigned)(d4.w - rlo);
        if (l0 < S) unsafeAtomicAdd(&acc[l0], DEG ? 1.0f : val[src[idx + 0]]);
        if (l1 < S) unsafeAtomicAdd(&acc[l1], DEG ? 1.0f : val[src[idx + 1]]);
        if (l2 < S) unsafeAtomicAdd(&acc[l2], DEG ? 1.0f : val[src[idx + 2]]);
        if (l3 < S) unsafeAtomicAdd(&acc[l3], DEG ? 1.0f : val[src[idx + 3]]);
    }
    // tail (e not multiple of 4)
    for (int i = (e4 << 2) + c * TPB + t; i < e; i += stride) {
        unsigned l = (unsigned)(dst[i] - rlo);
        if (l < S) unsafeAtomicAdd(&acc[l], DEG ? 1.0f : val[src[i]]);
    }

    __syncthreads();
    float* out = partials + (size_t)(r * bpr + c) * S;
    for (int j = t; j < S; j += TPB) out[j] = acc[j];
}

__device__ inline float reduce_partials(const float* __restrict__ partials,
                                        int n_idx, int bpr) {
    int r = n_idx >> LOG_S;
    int slot = n_idx & (S - 1);
    const float* p = partials + (size_t)r * bpr * S + slot;
    float s = 0.0f;
    for (int c = 0; c < bpr; c++) s += p[(size_t)c * S];
    return s;
}

__global__ void k_red_dinv(const float* __restrict__ partials, int bpr,
                           const float* __restrict__ x, float* __restrict__ dinv,
                           float* __restrict__ y, int n) {
    int i = blockIdx.x * blockDim.x + threadIdx.x;
    if (i < n) {
        float deg = reduce_partials(partials, i, bpr) + 1.0f;  // +1: self-loop
        float d = rsqrtf(deg);
        dinv[i] = d;
        y[i] = x[i] * d;
    }
}

__global__ void k_red_node(const float* __restrict__ partials, int bpr,
                           const float* __restrict__ dinv, const float* __restrict__ y,
                           float* __restrict__ z,
                           const float* __restrict__ W1, const float* __restrict__ b1,
                           const float* __restrict__ W2, int n, int f) {
    int i = blockIdx.x * blockDim.x + threadIdx.x;
    if (i < n) {
        float num = reduce_partials(partials, i, bpr);
        float agg = dinv[i] * (num + y[i]);   // + y[i]: self-loop term
        float h2 = 0.0f;
        for (int j = 0; j < f; j++) {
            float h = W1[j] * agg + b1[j];
            h2 += fmaxf(h, 0.0f) * W2[j];
        }
        z[i] = h2 * dinv[i];
    }
}

__global__ void k_red_out(const float* __restrict__ partials, int bpr,
                          const float* __restrict__ dinv, const float* __restrict__ z,
                          const float* __restrict__ b2, float* __restrict__ out, int n) {
    int i = blockIdx.x * blockDim.x + threadIdx.x;
    if (i < n) {
        float num = reduce_partials(partials, i, bpr);
        out[i] = dinv[i] * (num + z[i]) + b2[0];  // + z[i]: self-loop term
    }
}

// ---------------- fallback path (R1): device atomics ------------------------
__global__ void k_init(float* __restrict__ deg, float* __restrict__ num, int n) {
    int i = blockIdx.x * blockDim.x + threadIdx.x;
    if (i < n) { deg[i] = 1.0f; num[i] = 0.0f; }
}
__global__ void k_deg(const int* __restrict__ dst, float* __restrict__ deg, int e) {
    int i = blockIdx.x * blockDim.x + threadIdx.x;
    if (i < e) unsafeAtomicAdd(deg + dst[i], 1.0f);
}
__global__ void k_dinv(const float* __restrict__ x, float* __restrict__ deg_dinv,
                       float* __restrict__ y, int n) {
    int i = blockIdx.x * blockDim.x + threadIdx.x;
    if (i < n) { float d = rsqrtf(deg_dinv[i]); deg_dinv[i] = d; y[i] = x[i] * d; }
}
__global__ void k_scatter(const int* __restrict__ src, const int* __restrict__ dst,
                          const float* __restrict__ val, float* __restrict__ num, int e) {
    int i = blockIdx.x * blockDim.x + threadIdx.x;
    if (i < e) unsafeAtomicAdd(num + dst[i], val[src[i]]);
}
__global__ void k_node(const float* __restrict__ dinv, const float* __restrict__ y,
                       float* __restrict__ num, float* __restrict__ z,
                       const float* __restrict__ W1, const float* __restrict__ b1,
                       const float* __restrict__ W2, int n, int f) {
    int i = blockIdx.x * blockDim.x + threadIdx.x;
    if (i < n) {
        float agg = dinv[i] * (num[i] + y[i]);
        float h2 = 0.0f;
        for (int j = 0; j < f; j++) {
            float h = W1[j] * agg + b1[j];
            h2 += fmaxf(h, 0.0f) * W2[j];
        }
        z[i] = h2 * dinv[i];
        num[i] = 0.0f;
    }
}
__global__ void k_out(const float* __restrict__ dinv, const float* __restrict__ z,
                      const float* __restrict__ num, const float* __restrict__ b2,
                      float* __restrict__ out, int n) {
    int i = blockIdx.x * blockDim.x + threadIdx.x;
    if (i < n) out[i] = dinv[i] * (num[i] + z[i]) + b2[0];
}

extern "C" void kernel_launch(void* const* d_in, const int* in_sizes, int n_in,
                              void* d_out, int out_size, void* d_ws, size_t ws_size,
                              hipStream_t stream) {
    const float* x  = (const float*)d_in[0];
    const int*   ei = (const int*)d_in[1];
    const float* W1 = (const float*)d_in[2];
    const float* b1 = (const float*)d_in[3];
    const float* W2 = (const float*)d_in[4];
    const float* b2 = (const float*)d_in[5];

    int n = in_sizes[0];        // 200000
    int e = in_sizes[1] / 2;    // 12.8M
    int f = in_sizes[2];        // 16

    const int* src = ei;
    const int* dst = ei + e;

    float* A = (float*)d_ws;    // dinv
    float* B = A + n;           // y = x * dinv
    float* D = B + n;           // z = h2 * dinv
    float* out = (float*)d_out;

    int gn = (n + TPB - 1) / TPB;
    int R = (n + S - 1) / S;    // 13 ranges

    size_t node_bytes = (size_t)3 * n * sizeof(float);
    size_t per_c = (size_t)R * S * sizeof(float);   // 852 KB per c-slice
    int bpr = 0;
    if (ws_size > node_bytes) {
        size_t avail = ws_size - node_bytes;
        size_t m = avail / per_c;
        bpr = (int)(m > MAXC ? MAXC : m);
    }

    if (bpr >= 1) {
        float* partials = (float*)((char*)d_ws + node_bytes);
        int gs = R * bpr;   // e.g. 13*32 = 416 blocks, 2/CU (64 KB LDS)
        k_scat<true><<<gs, TPB, 0, stream>>>(dst, nullptr, nullptr, partials, e, bpr);
        k_red_dinv<<<gn, TPB, 0, stream>>>(partials, bpr, x, A, B, n);
        k_scat<false><<<gs, TPB, 0, stream>>>(dst, src, B, partials, e, bpr);
        k_red_node<<<gn, TPB, 0, stream>>>(partials, bpr, A, B, D, W1, b1, W2, n, f);
        k_scat<false><<<gs, TPB, 0, stream>>>(dst, src, D, partials, e, bpr);
        k_red_out<<<gn, TPB, 0, stream>>>(partials, bpr, A, D, b2, out, n);
    } else {
        // fallback: device-atomic path (R1)
        float* C = D + n;
        int ge = (e + TPB - 1) / TPB;
        k_init<<<gn, TPB, 0, stream>>>(A, C, n);
        k_deg<<<ge, TPB, 0, stream>>>(dst, A, e);
        k_dinv<<<gn, TPB, 0, stream>>>(x, A, B, n);
        k_scatter<<<ge, TPB, 0, stream>>>(src, dst, B, C, e);
        k_node<<<gn, TPB, 0, stream>>>(A, B, C, D, W1, b1, W2, n, f);
        k_scatter<<<ge, TPB, 0, stream>>>(src, dst, D, C, e);
        k_out<<<gn, TPB, 0, stream>>>(A, D, C, b2, out, n);
    }
}

// Round 4
// 502.071 us; speedup vs baseline: 4.0960x; 3.4538x over previous
//
#include <hip/hip_runtime.h>

#define TPB 256
#define STPB 512           // scatter block size
#define LOG_S 14
#define S (1 << LOG_S)     // 16384-node range per bucket -> 64 KB LDS acc
#define RMAX 32
#define CHUNK 4096         // edges per k_bin block
#define MAXC 40

// =============== binned path ================================================
// Edges are exactly binned by dst range (R = ceil(n/S) buckets) into a packed
// uint32 array: (dst - r*S) << 18 | src   (valid: n <= 2^18, S = 2^14).
// Scatter pass (r,c) then streams only bucket r: all lanes active,
// unconditional ds_add into 64 KB LDS acc, store partials, fused reduce.

__global__ void k_zero(int* __restrict__ p, int m) {
    int i = blockIdx.x * blockDim.x + threadIdx.x;
    if (i < m) p[i] = 0;
}

__global__ __launch_bounds__(TPB) void k_count(const int* __restrict__ dst, int e,
                                               int R, int* __restrict__ ghist) {
    __shared__ int h[RMAX];
    int t = threadIdx.x;
    if (t < R) h[t] = 0;
    __syncthreads();
    int e4 = e >> 2;
    const int4* d4p = (const int4*)dst;
    int stride = gridDim.x * blockDim.x;
    for (int i = blockIdx.x * blockDim.x + t; i < e4; i += stride) {
        int4 d = d4p[i];
        atomicAdd(&h[d.x >> LOG_S], 1);
        atomicAdd(&h[d.y >> LOG_S], 1);
        atomicAdd(&h[d.z >> LOG_S], 1);
        atomicAdd(&h[d.w >> LOG_S], 1);
    }
    for (int i = (e4 << 2) + blockIdx.x * blockDim.x + t; i < e; i += stride)
        atomicAdd(&h[dst[i] >> LOG_S], 1);
    __syncthreads();
    if (t < R && h[t]) atomicAdd(&ghist[t], h[t]);
}

__global__ void k_scan(const int* __restrict__ ghist, int R,
                       int* __restrict__ boff, int* __restrict__ blen,
                       int* __restrict__ cursors) {
    if (threadIdx.x == 0 && blockIdx.x == 0) {
        int off = 0;
        for (int r = 0; r < R; r++) {
            boff[r] = off;
            blen[r] = ghist[r];
            cursors[r] = off;
            off = (off + ghist[r] + 3) & ~3;   // keep bucket bases 16B-aligned
        }
        boff[R] = off;
    }
}

__global__ __launch_bounds__(TPB) void k_bin(const int* __restrict__ dst,
                                             const int* __restrict__ src, int e,
                                             int R, int* __restrict__ cursors,
                                             unsigned* __restrict__ buckets) {
    __shared__ unsigned lpack[CHUNK];
    __shared__ unsigned char lrr[CHUNK];
    __shared__ unsigned stage[CHUNK];
    __shared__ int h[RMAX], lofs[RMAX], gbase[RMAX], c2[RMAX];
    int t = threadIdx.x;
    int b0 = blockIdx.x * CHUNK;
    int m = min(CHUNK, e - b0);
    if (t < R) { h[t] = 0; c2[t] = 0; }
    __syncthreads();
    for (int j = t; j < m; j += TPB) {
        int d = dst[b0 + j];
        int s = src[b0 + j];
        int r = d >> LOG_S;
        lpack[j] = ((unsigned)(d - (r << LOG_S)) << 18) | (unsigned)s;
        lrr[j] = (unsigned char)r;
        atomicAdd(&h[r], 1);
    }
    __syncthreads();
    if (t == 0) {
        int o = 0;
        for (int r = 0; r < R; r++) { lofs[r] = o; o += h[r]; }
    }
    __syncthreads();
    if (t < R && h[t] > 0) gbase[t] = atomicAdd(&cursors[t], h[t]);
    __syncthreads();
    for (int j = t; j < m; j += TPB) {
        int r = lrr[j];
        int sl = lofs[r] + atomicAdd(&c2[r], 1);
        stage[sl] = lpack[j];
    }
    __syncthreads();
    for (int r = 0; r < R; r++) {          // coalesced per-bucket segment copy
        int cnt = h[r], lo = lofs[r], gb = gbase[r];
        for (int j = t; j < cnt; j += TPB) buckets[gb + j] = stage[lo + j];
    }
}

template <bool DEG>
__global__ __launch_bounds__(STPB) void k_scat(const unsigned* __restrict__ buckets,
                                               const int* __restrict__ boff,
                                               const int* __restrict__ blen,
                                               const float* __restrict__ val,
                                               float* __restrict__ partials, int bpr) {
    __shared__ float acc[S];
    int t = threadIdx.x;
    int r = blockIdx.x / bpr;
    int c = blockIdx.x - r * bpr;
    for (int j = t; j < S; j += STPB) acc[j] = 0.0f;
    __syncthreads();
    const unsigned* bk = buckets + boff[r];
    int len = blen[r];
    int len4 = len >> 2;
    const uint4* bk4 = (const uint4*)bk;
    int stride = bpr * STPB;
    for (int i = c * STPB + t; i < len4; i += stride) {
        uint4 p = bk4[i];
        unsafeAtomicAdd(&acc[p.x >> 18], DEG ? 1.0f : val[p.x & 0x3FFFFu]);
        unsafeAtomicAdd(&acc[p.y >> 18], DEG ? 1.0f : val[p.y & 0x3FFFFu]);
        unsafeAtomicAdd(&acc[p.z >> 18], DEG ? 1.0f : val[p.z & 0x3FFFFu]);
        unsafeAtomicAdd(&acc[p.w >> 18], DEG ? 1.0f : val[p.w & 0x3FFFFu]);
    }
    for (int i = (len4 << 2) + c * STPB + t; i < len; i += stride) {
        unsigned p = bk[i];
        unsafeAtomicAdd(&acc[p >> 18], DEG ? 1.0f : val[p & 0x3FFFFu]);
    }
    __syncthreads();
    float* out = partials + (size_t)blockIdx.x * S;   // [r][c][S] layout
    for (int j = t; j < S; j += STPB) out[j] = acc[j];
}

__device__ inline float reduce_partials(const float* __restrict__ partials,
                                        int n_idx, int bpr) {
    int r = n_idx >> LOG_S;
    int slot = n_idx & (S - 1);
    const float* p = partials + (size_t)r * bpr * S + slot;
    float s = 0.0f;
    for (int c = 0; c < bpr; c++) s += p[(size_t)c * S];
    return s;
}

__global__ void k_red_dinv(const float* __restrict__ partials, int bpr,
                           const float* __restrict__ x, float* __restrict__ dinv,
                           float* __restrict__ y, int n) {
    int i = blockIdx.x * blockDim.x + threadIdx.x;
    if (i < n) {
        float deg = reduce_partials(partials, i, bpr) + 1.0f;  // +1: self-loop
        float d = rsqrtf(deg);
        dinv[i] = d;
        y[i] = x[i] * d;
    }
}

__global__ void k_red_node(const float* __restrict__ partials, int bpr,
                           const float* __restrict__ dinv, const float* __restrict__ y,
                           float* __restrict__ z,
                           const float* __restrict__ W1, const float* __restrict__ b1,
                           const float* __restrict__ W2, int n, int f) {
    int i = blockIdx.x * blockDim.x + threadIdx.x;
    if (i < n) {
        float num = reduce_partials(partials, i, bpr);
        float agg = dinv[i] * (num + y[i]);   // + y[i]: self-loop term
        float h2 = 0.0f;
        for (int j = 0; j < f; j++) {
            float h = W1[j] * agg + b1[j];
            h2 += fmaxf(h, 0.0f) * W2[j];
        }
        z[i] = h2 * dinv[i];
    }
}

__global__ void k_red_out(const float* __restrict__ partials, int bpr,
                          const float* __restrict__ dinv, const float* __restrict__ z,
                          const float* __restrict__ b2, float* __restrict__ out, int n) {
    int i = blockIdx.x * blockDim.x + threadIdx.x;
    if (i < n) {
        float num = reduce_partials(partials, i, bpr);
        out[i] = dinv[i] * (num + z[i]) + b2[0];  // + z[i]: self-loop term
    }
}

// =============== fallback path (R3, proven): unbinned LDS scatter ===========
template <bool DEG>
__global__ __launch_bounds__(TPB) void k_scat_f(const int* __restrict__ dst,
                                                const int* __restrict__ src,
                                                const float* __restrict__ val,
                                                float* __restrict__ partials,
                                                int e, int bpr) {
    __shared__ float acc[S];
    const int t = threadIdx.x;
    const int r = blockIdx.x / bpr;
    const int c = blockIdx.x - r * bpr;
    const int rlo = r << LOG_S;
    for (int j = t; j < S; j += TPB) acc[j] = 0.0f;
    __syncthreads();
    const int stride = bpr * TPB;
    const int e4 = e >> 2;
    const int4* dst4 = (const int4*)dst;
    for (int i = c * TPB + t; i < e4; i += stride) {
        int4 d4 = dst4[i];
        int idx = i << 2;
        unsigned l0 = (unsigned)(d4.x - rlo), l1 = (unsigned)(d4.y - rlo);
        unsigned l2 = (unsigned)(d4.z - rlo), l3 = (unsigned)(d4.w - rlo);
        if (l0 < S) unsafeAtomicAdd(&acc[l0], DEG ? 1.0f : val[src[idx + 0]]);
        if (l1 < S) unsafeAtomicAdd(&acc[l1], DEG ? 1.0f : val[src[idx + 1]]);
        if (l2 < S) unsafeAtomicAdd(&acc[l2], DEG ? 1.0f : val[src[idx + 2]]);
        if (l3 < S) unsafeAtomicAdd(&acc[l3], DEG ? 1.0f : val[src[idx + 3]]);
    }
    for (int i = (e4 << 2) + c * TPB + t; i < e; i += stride) {
        unsigned l = (unsigned)(dst[i] - rlo);
        if (l < S) unsafeAtomicAdd(&acc[l], DEG ? 1.0f : val[src[i]]);
    }
    __syncthreads();
    float* out = partials + (size_t)(r * bpr + c) * S;
    for (int j = t; j < S; j += TPB) out[j] = acc[j];
}

extern "C" void kernel_launch(void* const* d_in, const int* in_sizes, int n_in,
                              void* d_out, int out_size, void* d_ws, size_t ws_size,
                              hipStream_t stream) {
    const float* x  = (const float*)d_in[0];
    const int*   ei = (const int*)d_in[1];
    const float* W1 = (const float*)d_in[2];
    const float* b1 = (const float*)d_in[3];
    const float* W2 = (const float*)d_in[4];
    const float* b2 = (const float*)d_in[5];

    int n = in_sizes[0];        // 200000
    int e = in_sizes[1] / 2;    // 12.8M
    int f = in_sizes[2];        // 16

    const int* src = ei;
    const int* dst = ei + e;
    float* out = (float*)d_out;

    int R  = (n + S - 1) >> LOG_S;                  // 13
    int gn = (n + TPB - 1) / TPB;

    // ws layout in 4-byte words
    size_t o_A    = 0;                              // dinv   (n)
    size_t o_B    = o_A + n;                        // y      (n)
    size_t o_D    = o_B + n;                        // z      (n)
    size_t o_hist = o_D + n;                        // RMAX
    size_t o_boff = o_hist + RMAX;                  // RMAX+1
    size_t o_blen = o_boff + RMAX + 1;              // RMAX
    size_t o_cur  = o_blen + RMAX;                  // RMAX
    size_t o_bkt  = (o_cur + RMAX + 3) & ~(size_t)3;
    size_t bkcap  = (size_t)e + 4 * RMAX;
    size_t o_part = o_bkt + bkcap;                  // stays 16B-aligned (e%4==0)
    size_t words  = ws_size / 4;

    float* A = (float*)d_ws + o_A;
    float* B = (float*)d_ws + o_B;
    float* D = (float*)d_ws + o_D;
    int*   hist = (int*)d_ws + o_hist;
    int*   boff = (int*)d_ws + o_boff;
    int*   blen = (int*)d_ws + o_blen;
    int*   cur  = (int*)d_ws + o_cur;
    unsigned* bkt = (unsigned*)d_ws + o_bkt;

    int bpr = 0;
    if (R <= RMAX && n <= (1 << 18) && words > o_part) {
        size_t per_c = (size_t)R * S;
        size_t m = (words - o_part) / per_c;
        bpr = (int)(m > MAXC ? MAXC : m);
    }

    if (bpr >= 4) {
        float* partials = (float*)d_ws + o_part;
        int gs = R * bpr;                           // e.g. 13*40 = 520 blocks
        int gbin = (e + CHUNK - 1) / CHUNK;         // 3125
        k_zero<<<1, 64, 0, stream>>>(hist, RMAX);
        k_count<<<512, TPB, 0, stream>>>(dst, e, R, hist);
        k_scan<<<1, 64, 0, stream>>>(hist, R, boff, blen, cur);
        k_bin<<<gbin, TPB, 0, stream>>>(dst, src, e, R, cur, bkt);
        k_scat<true><<<gs, STPB, 0, stream>>>(bkt, boff, blen, nullptr, partials, bpr);
        k_red_dinv<<<gn, TPB, 0, stream>>>(partials, bpr, x, A, B, n);
        k_scat<false><<<gs, STPB, 0, stream>>>(bkt, boff, blen, B, partials, bpr);
        k_red_node<<<gn, TPB, 0, stream>>>(partials, bpr, A, B, D, W1, b1, W2, n, f);
        k_scat<false><<<gs, STPB, 0, stream>>>(bkt, boff, blen, D, partials, bpr);
        k_red_out<<<gn, TPB, 0, stream>>>(partials, bpr, A, D, b2, out, n);
    } else {
        // fallback: unbinned multi-pass (proven R3 path)
        size_t node_w = (size_t)3 * n;
        size_t per_c = (size_t)R * S;
        int bpr2 = 0;
        if (words > node_w) {
            size_t m = (words - node_w) / per_c;
            bpr2 = (int)(m > 32 ? 32 : m);
        }
        float* partials = (float*)d_ws + node_w;
        int gs = R * bpr2;
        k_scat_f<true><<<gs, TPB, 0, stream>>>(dst, nullptr, nullptr, partials, e, bpr2);
        k_red_dinv<<<gn, TPB, 0, stream>>>(partials, bpr2, x, A, B, n);
        k_scat_f<false><<<gs, TPB, 0, stream>>>(dst, src, B, partials, e, bpr2);
        k_red_node<<<gn, TPB, 0, stream>>>(partials, bpr2, A, B, D, W1, b1, W2, n, f);
        k_scat_f<false><<<gs, TPB, 0, stream>>>(dst, src, D, partials, e, bpr2);
        k_red_out<<<gn, TPB, 0, stream>>>(partials, bpr2, A, D, b2, out, n);
    }
}

// Round 5
// 482.320 us; speedup vs baseline: 4.2637x; 1.0409x over previous
//
#include <hip/hip_runtime.h>

#define TPB 256            // generic node-pass block size
#define BTPB 512           // k_bin block size
#define STPB 512           // k_scat block size
#define LOG_S 13
#define S (1 << LOG_S)     // 8192-node range -> 32 KB LDS acc -> 4 blocks/CU
#define RMAX 32
#define CHUNK 4096         // edges per k_bin block
#define MAXC 32            // scatter c-splits per range

// Edges binned by dst range (R = ceil(n/S)) into packed uint32:
// (dst - r*S) << 18 | src   (needs n <= 2^18, S <= 2^13 local -> 13 bits).
// Scatter (r,c): stream bucket r stripe c, unconditional ds_add into 32 KB
// LDS acc, float4 flush to partials, fused reduce + pointwise epilogue.

__global__ void k_zero(int* __restrict__ p, int m) {
    int i = blockIdx.x * blockDim.x + threadIdx.x;
    if (i < m) p[i] = 0;
}

__global__ __launch_bounds__(TPB) void k_count(const int* __restrict__ dst, int e,
                                               int R, int* __restrict__ ghist) {
    __shared__ int h[RMAX];
    int t = threadIdx.x;
    if (t < R) h[t] = 0;
    __syncthreads();
    int e4 = e >> 2;
    const int4* d4p = (const int4*)dst;
    int stride = gridDim.x * blockDim.x;
    for (int i = blockIdx.x * blockDim.x + t; i < e4; i += stride) {
        int4 d = d4p[i];
        atomicAdd(&h[d.x >> LOG_S], 1);
        atomicAdd(&h[d.y >> LOG_S], 1);
        atomicAdd(&h[d.z >> LOG_S], 1);
        atomicAdd(&h[d.w >> LOG_S], 1);
    }
    for (int i = (e4 << 2) + blockIdx.x * blockDim.x + t; i < e; i += stride)
        atomicAdd(&h[dst[i] >> LOG_S], 1);
    __syncthreads();
    if (t < R && h[t]) atomicAdd(&ghist[t], h[t]);
}

__global__ void k_scan(const int* __restrict__ ghist, int R,
                       int* __restrict__ boff, int* __restrict__ blen,
                       int* __restrict__ cursors) {
    if (threadIdx.x == 0 && blockIdx.x == 0) {
        int off = 0;
        for (int r = 0; r < R; r++) {
            boff[r] = off;
            blen[r] = ghist[r];
            cursors[r] = off;
            off = (off + ghist[r] + 3) & ~3;   // 16B-aligned bucket bases
        }
        boff[R] = off;
    }
}

__global__ __launch_bounds__(BTPB) void k_bin(const int* __restrict__ dst,
                                              const int* __restrict__ src, int e,
                                              int R, int* __restrict__ cursors,
                                              unsigned* __restrict__ buckets) {
    __shared__ unsigned lpack[CHUNK];
    __shared__ unsigned char lrr[CHUNK];
    __shared__ unsigned stage[CHUNK];
    __shared__ int h[RMAX], lofs[RMAX + 1], gbase[RMAX], c2[RMAX];
    int t = threadIdx.x;
    int b0 = blockIdx.x * CHUNK;
    int m = min(CHUNK, e - b0);
    if (t < RMAX) { h[t] = 0; c2[t] = 0; }
    __syncthreads();
    for (int j = t; j < m; j += BTPB) {
        int d = dst[b0 + j];
        int s = src[b0 + j];
        int r = d >> LOG_S;
        lpack[j] = ((unsigned)(d - (r << LOG_S)) << 18) | (unsigned)s;
        lrr[j] = (unsigned char)r;
        atomicAdd(&h[r], 1);
    }
    __syncthreads();
    if (t < 64) {                      // wave-0 exclusive scan + reservation
        int hv = (t < R) ? h[t] : 0;
        int v = hv;
        for (int o = 1; o < 64; o <<= 1) {
            int u = __shfl_up(v, o);
            if (t >= o) v += u;
        }
        if (t < R) lofs[t] = v - hv;
        if (t == R - 1) lofs[R] = v;   // total = m
        if (t < R && hv > 0) gbase[t] = atomicAdd(&cursors[t], hv);
    }
    __syncthreads();
    for (int j = t; j < m; j += BTPB) {
        int r = lrr[j];
        int sl = lofs[r] + atomicAdd(&c2[r], 1);
        stage[sl] = lpack[j];
    }
    __syncthreads();
    for (int j = t; j < m; j += BTPB) {     // dense copy, bsearch segment
        int lo = 0, hi = R;
        while (hi - lo > 1) {
            int mid = (lo + hi) >> 1;
            if (lofs[mid] <= j) lo = mid; else hi = mid;
        }
        buckets[gbase[lo] + (j - lofs[lo])] = stage[j];
    }
}

template <bool DEG>
__global__ __launch_bounds__(STPB) void k_scat(const unsigned* __restrict__ buckets,
                                               const int* __restrict__ boff,
                                               const int* __restrict__ blen,
                                               const float* __restrict__ val,
                                               float* __restrict__ partials, int bpr) {
    __shared__ float acc[S];
    int t = threadIdx.x;
    int r = blockIdx.x / bpr;
    int c = blockIdx.x - r * bpr;
    float4* acc4 = (float4*)acc;
    for (int j = t; j < S / 4; j += STPB) acc4[j] = make_float4(0.f, 0.f, 0.f, 0.f);
    __syncthreads();
    const unsigned* bk = buckets + boff[r];
    int len = blen[r];
    int len4 = len >> 2;
    const uint4* bk4 = (const uint4*)bk;
    int stride = bpr * STPB;
    int i = c * STPB + t;
    if (i < len4) {
        uint4 p = bk4[i];
        for (; i < len4; ) {
            int inext = i + stride;
            uint4 pn;
            if (inext < len4) pn = bk4[inext];     // prefetch next
            unsafeAtomicAdd(&acc[p.x >> 18], DEG ? 1.0f : val[p.x & 0x3FFFFu]);
            unsafeAtomicAdd(&acc[p.y >> 18], DEG ? 1.0f : val[p.y & 0x3FFFFu]);
            unsafeAtomicAdd(&acc[p.z >> 18], DEG ? 1.0f : val[p.z & 0x3FFFFu]);
            unsafeAtomicAdd(&acc[p.w >> 18], DEG ? 1.0f : val[p.w & 0x3FFFFu]);
            p = pn;
            i = inext;
        }
    }
    for (int k = (len4 << 2) + c * STPB + t; k < len; k += stride) {
        unsigned p = bk[k];
        unsafeAtomicAdd(&acc[p >> 18], DEG ? 1.0f : val[p & 0x3FFFFu]);
    }
    __syncthreads();
    float4* out4 = (float4*)(partials + (size_t)blockIdx.x * S);   // [r][c][S]
    for (int j = t; j < S / 4; j += STPB) out4[j] = acc4[j];
}

__device__ inline float reduce_partials(const float* __restrict__ partials,
                                        int n_idx, int bpr) {
    int r = n_idx >> LOG_S;
    int slot = n_idx & (S - 1);
    const float* p = partials + (size_t)r * bpr * S + slot;
    float s = 0.0f;
    for (int c = 0; c < bpr; c++) s += p[(size_t)c * S];
    return s;
}

__global__ void k_red_dinv(const float* __restrict__ partials, int bpr,
                           const float* __restrict__ x, float* __restrict__ dinv,
                           float* __restrict__ y, int n) {
    int i = blockIdx.x * blockDim.x + threadIdx.x;
    if (i < n) {
        float deg = reduce_partials(partials, i, bpr) + 1.0f;  // +1: self-loop
        float d = rsqrtf(deg);
        dinv[i] = d;
        y[i] = x[i] * d;
    }
}

__global__ void k_red_node(const float* __restrict__ partials, int bpr,
                           const float* __restrict__ dinv, const float* __restrict__ y,
                           float* __restrict__ z,
                           const float* __restrict__ W1, const float* __restrict__ b1,
                           const float* __restrict__ W2, int n, int f) {
    int i = blockIdx.x * blockDim.x + threadIdx.x;
    if (i < n) {
        float num = reduce_partials(partials, i, bpr);
        float agg = dinv[i] * (num + y[i]);   // + y[i]: self-loop term
        float h2 = 0.0f;
        for (int j = 0; j < f; j++) {
            float h = W1[j] * agg + b1[j];
            h2 += fmaxf(h, 0.0f) * W2[j];
        }
        z[i] = h2 * dinv[i];
    }
}

__global__ void k_red_out(const float* __restrict__ partials, int bpr,
                          const float* __restrict__ dinv, const float* __restrict__ z,
                          const float* __restrict__ b2, float* __restrict__ out, int n) {
    int i = blockIdx.x * blockDim.x + threadIdx.x;
    if (i < n) {
        float num = reduce_partials(partials, i, bpr);
        out[i] = dinv[i] * (num + z[i]) + b2[0];  // + z[i]: self-loop term
    }
}

// =============== fallback: unbinned LDS scatter (R3-proven structure) =======
template <bool DEG>
__global__ __launch_bounds__(TPB) void k_scat_f(const int* __restrict__ dst,
                                                const int* __restrict__ src,
                                                const float* __restrict__ val,
                                                float* __restrict__ partials,
                                                int e, int bpr) {
    __shared__ float acc[S];
    const int t = threadIdx.x;
    const int r = blockIdx.x / bpr;
    const int c = blockIdx.x - r * bpr;
    const int rlo = r << LOG_S;
    for (int j = t; j < S; j += TPB) acc[j] = 0.0f;
    __syncthreads();
    const int stride = bpr * TPB;
    const int e4 = e >> 2;
    const int4* dst4 = (const int4*)dst;
    for (int i = c * TPB + t; i < e4; i += stride) {
        int4 d4 = dst4[i];
        int idx = i << 2;
        unsigned l0 = (unsigned)(d4.x - rlo), l1 = (unsigned)(d4.y - rlo);
        unsigned l2 = (unsigned)(d4.z - rlo), l3 = (unsigned)(d4.w - rlo);
        if (l0 < S) unsafeAtomicAdd(&acc[l0], DEG ? 1.0f : val[src[idx + 0]]);
        if (l1 < S) unsafeAtomicAdd(&acc[l1], DEG ? 1.0f : val[src[idx + 1]]);
        if (l2 < S) unsafeAtomicAdd(&acc[l2], DEG ? 1.0f : val[src[idx + 2]]);
        if (l3 < S) unsafeAtomicAdd(&acc[l3], DEG ? 1.0f : val[src[idx + 3]]);
    }
    for (int i = (e4 << 2) + c * TPB + t; i < e; i += stride) {
        unsigned l = (unsigned)(dst[i] - rlo);
        if (l < S) unsafeAtomicAdd(&acc[l], DEG ? 1.0f : val[src[i]]);
    }
    __syncthreads();
    float* out = partials + (size_t)(r * bpr + c) * S;
    for (int j = t; j < S; j += TPB) out[j] = acc[j];
}

extern "C" void kernel_launch(void* const* d_in, const int* in_sizes, int n_in,
                              void* d_out, int out_size, void* d_ws, size_t ws_size,
                              hipStream_t stream) {
    const float* x  = (const float*)d_in[0];
    const int*   ei = (const int*)d_in[1];
    const float* W1 = (const float*)d_in[2];
    const float* b1 = (const float*)d_in[3];
    const float* W2 = (const float*)d_in[4];
    const float* b2 = (const float*)d_in[5];

    int n = in_sizes[0];        // 200000
    int e = in_sizes[1] / 2;    // 12.8M
    int f = in_sizes[2];        // 16

    const int* src = ei;
    const int* dst = ei + e;
    float* out = (float*)d_out;

    int R  = (n + S - 1) >> LOG_S;                  // 25
    int gn = (n + TPB - 1) / TPB;

    // ws layout in 4-byte words
    size_t o_A    = 0;                              // dinv   (n)
    size_t o_B    = o_A + n;                        // y      (n)
    size_t o_D    = o_B + n;                        // z      (n)
    size_t o_hist = o_D + n;                        // RMAX
    size_t o_boff = o_hist + RMAX;                  // RMAX+1
    size_t o_blen = o_boff + RMAX + 1;              // RMAX
    size_t o_cur  = o_blen + RMAX;                  // RMAX
    size_t o_bkt  = (o_cur + RMAX + 3) & ~(size_t)3;
    size_t bkcap  = (size_t)e + 4 * RMAX;
    size_t o_part = o_bkt + bkcap;                  // 16B-aligned (e%4==0)
    size_t words  = ws_size / 4;

    float* A = (float*)d_ws + o_A;
    float* B = (float*)d_ws + o_B;
    float* D = (float*)d_ws + o_D;
    int*   hist = (int*)d_ws + o_hist;
    int*   boff = (int*)d_ws + o_boff;
    int*   blen = (int*)d_ws + o_blen;
    int*   cur  = (int*)d_ws + o_cur;
    unsigned* bkt = (unsigned*)d_ws + o_bkt;

    int bpr = 0;
    if (R <= RMAX && n <= (1 << 18) && words > o_part) {
        size_t per_c = (size_t)R * S;
        size_t m = (words - o_part) / per_c;
        bpr = (int)(m > MAXC ? MAXC : m);
    }

    if (bpr >= 4) {
        float* partials = (float*)d_ws + o_part;
        int gs = R * bpr;                           // e.g. 25*32 = 800 blocks
        int gbin = (e + CHUNK - 1) / CHUNK;         // 3125
        k_zero<<<1, 64, 0, stream>>>(hist, RMAX);
        k_count<<<512, TPB, 0, stream>>>(dst, e, R, hist);
        k_scan<<<1, 64, 0, stream>>>(hist, R, boff, blen, cur);
        k_bin<<<gbin, BTPB, 0, stream>>>(dst, src, e, R, cur, bkt);
        k_scat<true><<<gs, STPB, 0, stream>>>(bkt, boff, blen, nullptr, partials, bpr);
        k_red_dinv<<<gn, TPB, 0, stream>>>(partials, bpr, x, A, B, n);
        k_scat<false><<<gs, STPB, 0, stream>>>(bkt, boff, blen, B, partials, bpr);
        k_red_node<<<gn, TPB, 0, stream>>>(partials, bpr, A, B, D, W1, b1, W2, n, f);
        k_scat<false><<<gs, STPB, 0, stream>>>(bkt, boff, blen, D, partials, bpr);
        k_red_out<<<gn, TPB, 0, stream>>>(partials, bpr, A, D, b2, out, n);
    } else {
        // fallback: unbinned multi-pass
        size_t node_w = (size_t)3 * n;
        size_t per_c = (size_t)R * S;
        int bpr2 = 0;
        if (words > node_w) {
            size_t m = (words - node_w) / per_c;
            bpr2 = (int)(m > 32 ? 32 : m);
        }
        float* partials = (float*)d_ws + node_w;
        int gs = R * bpr2;
        k_scat_f<true><<<gs, TPB, 0, stream>>>(dst, nullptr, nullptr, partials, e, bpr2);
        k_red_dinv<<<gn, TPB, 0, stream>>>(partials, bpr2, x, A, B, n);
        k_scat_f<false><<<gs, TPB, 0, stream>>>(dst, src, B, partials, e, bpr2);
        k_red_node<<<gn, TPB, 0, stream>>>(partials, bpr2, A, B, D, W1, b1, W2, n, f);
        k_scat_f<false><<<gs, TPB, 0, stream>>>(dst, src, D, partials, e, bpr2);
        k_red_out<<<gn, TPB, 0, stream>>>(partials, bpr2, A, D, b2, out, n);
    }
}